// Round 8
// baseline (411.169 us; speedup 1.0000x reference)
//
#include <hip/hip_runtime.h>
#include <math.h>

// Problem constants
#define N_Q    32768
#define N_E    262144
// dims: IN=EMB=192, concat=384, 2*HID=384, BOT=192, PREDH=192, OUT=4

typedef _Float16 half8 __attribute__((ext_vector_type(8)));
typedef _Float16 half4v __attribute__((ext_vector_type(4)));
typedef float f32x4 __attribute__((ext_vector_type(4)));

// A&S 7.1.25 erf (|eps|<=2.5e-5). gelu(x)=0.5(x+|x|*erf(|x|/sqrt2))
__device__ __forceinline__ float gelu_f(float x) {
    float ax = fabsf(x);
    float t = __builtin_amdgcn_rcpf(fmaf(0.33269070724668f, ax, 1.0f));
    float poly = t * fmaf(t, fmaf(t, 0.7478556f, -0.0958798f), 0.3480242f);
    float e = exp2f(-0.72134752044448f * ax * ax);
    float u = fmaf(-poly, e, 1.0f);          // erf(z)
    return 0.5f * fmaf(ax, u, x);
}

// ---- pack W[K][N] fp32 -> fragment-order f16 ----
// Per (n_tile, ks) a 1KB block; lane l holds B[k=ks*32+(l>>4)*8+j][n=n_tile*16+(l&15)]
__device__ __forceinline__ void pack_one(const float* __restrict__ W,
                                         _Float16* __restrict__ Wp,
                                         int K, int N, int blk0, int tid) {
    int u = blk0 * 256 + tid;                   // one half8 per thread
    if (u * 8 >= K * N) return;
    int l = u & 63, blk = u >> 6;
    int nks = K >> 5;
    int ntile = blk / nks, ks = blk - ntile * nks;
    int n = ntile * 16 + (l & 15);
    int k0 = ks * 32 + (l >> 4) * 8;
    half8 v;
    #pragma unroll
    for (int j = 0; j < 8; ++j) v[j] = (_Float16)W[(size_t)(k0 + j) * N + n];
    *(half8*)(Wp + (size_t)u * 8) = v;
}

// ---------------- fused prep: embed | pack all 5 W ----------------
// blocks [0,12288): embed; [12288,12504): pack
__global__ __launch_bounds__(256) void prep_kernel(
    const float* __restrict__ qpos, _Float16* __restrict__ qe,
    const float* __restrict__ pw,  _Float16* __restrict__ WpP,
    const float* __restrict__ m0,  _Float16* __restrict__ Wp0,
    const float* __restrict__ m1,  _Float16* __restrict__ Wp1,
    const float* __restrict__ m2,  _Float16* __restrict__ Wp2,
    const float* __restrict__ hw,  _Float16* __restrict__ WpH)
{
    const int b = blockIdx.x, t = threadIdx.x;
    if (b < 12288) {
        // sincos embedding -> f16 (hw sin/cos on revolutions)
        int gid = b * 256 + t;                  // covers N_Q*96: (q, d, i)
        int q = gid / 96, r = gid - q * 96;
        int d = r >> 5, i = r & 31;
        float omega = exp2f(-(float)i * 0.41524101186092029f);  // log2(10000)/32
        float arg = qpos[q * 3 + d] * omega;
        float rev = arg * 0.15915494309189535f;                 // rad -> revolutions
        rev = rev - floorf(rev);
        float s = __builtin_amdgcn_sinf(rev);
        float c = __builtin_amdgcn_cosf(rev);
        int base = q * 192 + d * 64 + i;
        qe[base] = (_Float16)s;
        qe[base + 32] = (_Float16)c;
    } else {
        int bb = b - 12288;
        if      (bb < 18)  pack_one(pw, WpP, 192, 192, bb,       t);
        else if (bb < 90)  pack_one(m0, Wp0, 384, 384, bb - 18,  t);
        else if (bb < 162) pack_one(m1, Wp1, 384, 384, bb - 90,  t);
        else if (bb < 198) pack_one(m2, Wp2, 384, 192, bb - 162, t);
        else               pack_one(hw, WpH, 192, 192, bb - 198, t);
    }
}

// ---------------- proj: xf = f16(x @ proj_w + proj_b), via MFMA ----------------
#define PK 200   // hA row stride (f16), 400 B

__global__ __launch_bounds__(256, 2) void proj_mfma_kernel(
    const float* __restrict__ x, const _Float16* __restrict__ Wp,
    const float* __restrict__ bias, _Float16* __restrict__ xf)
{
    __shared__ _Float16 hA[64 * PK];   // 25600 B
    const int t = threadIdx.x;
    const int r0 = blockIdx.x * 64;
    const int lane = t & 63;
    const int w = t >> 6;
    const int ln = lane & 15, lq = lane >> 4;

    #pragma unroll
    for (int i = 0; i < 12; ++i) {                 // 3072 float4s
        int idx = t + 256 * i;
        int r = idx / 48, c4 = idx - r * 48;
        float4 v = ((const float4*)(x + (size_t)(r0 + r) * 192))[c4];
        half4v hv; hv[0] = (_Float16)v.x; hv[1] = (_Float16)v.y;
        hv[2] = (_Float16)v.z; hv[3] = (_Float16)v.w;
        *(half4v*)(hA + r * PK + c4 * 4) = hv;
    }
    __syncthreads();

    f32x4 acc[4][3];
    #pragma unroll
    for (int nt = 0; nt < 3; ++nt) {
        float bv = bias[w * 48 + nt * 16 + ln];
        #pragma unroll
        for (int mt = 0; mt < 4; ++mt) acc[mt][nt] = (f32x4){bv, bv, bv, bv};
    }
    const _Float16* abase = hA + ln * PK + lq * 8;
    #pragma unroll 2
    for (int ks = 0; ks < 6; ++ks) {
        half8 a[4], bf[3];
        #pragma unroll
        for (int mt = 0; mt < 4; ++mt)
            a[mt] = *(const half8*)(abase + mt * 16 * PK + ks * 32);
        #pragma unroll
        for (int nt = 0; nt < 3; ++nt)
            bf[nt] = *(const half8*)(Wp + (size_t)(((w * 3 + nt) * 6 + ks) * 512 + lane * 8));
        #pragma unroll
        for (int nt = 0; nt < 3; ++nt)
            #pragma unroll
            for (int mt = 0; mt < 4; ++mt)
                acc[mt][nt] = __builtin_amdgcn_mfma_f32_16x16x32_f16(a[mt], bf[nt], acc[mt][nt], 0, 0, 0);
    }
    #pragma unroll
    for (int mt = 0; mt < 4; ++mt)
        #pragma unroll
        for (int nt = 0; nt < 3; ++nt)
            #pragma unroll
            for (int r = 0; r < 4; ++r) {
                int m = mt * 16 + lq * 4 + r;
                int n = w * 48 + nt * 16 + ln;
                xf[(size_t)(r0 + m) * 192 + n] = (_Float16)acc[mt][nt][r];
            }
}

// ---------------- fused edge MLP via f16 MFMA, 512 threads / 8 waves ----------------
#define PADK 392   // hA row stride in f16 elements (784 B)

__global__ __launch_bounds__(512, 6) void edge_mlp_kernel(
    const _Float16* __restrict__ xf, const _Float16* __restrict__ qe,
    const int* __restrict__ edges,
    const _Float16* __restrict__ Wp0, const float* __restrict__ b0,
    const _Float16* __restrict__ Wp1, const float* __restrict__ b1,
    const _Float16* __restrict__ Wp2, const float* __restrict__ b2,
    float* __restrict__ seg, float* __restrict__ cnt)
{
    __shared__ _Float16 hA[64 * PADK];   // 50176 B; aliased as f32 h2[64][192] later
    __shared__ int qi[64], gi[64];
    float* h2 = (float*)hA;

    const int t = threadIdx.x;
    const int e0 = blockIdx.x * 64;
    const int lane = t & 63;
    const int w = t >> 6;                // 0..7
    const int ln = lane & 15;            // MFMA n / m low index
    const int lq = lane >> 4;            // quad

    if (t < 64) {
        qi[t] = edges[2 * (e0 + t)];
        gi[t] = edges[2 * (e0 + t) + 1];
    }
    __syncthreads();

    // ---- gather concat(xf[g], qe[q]) into padded LDS (R5 pattern: contiguous
    // chunk-space per wave — R6's row×sub decomposition doubled edge HBM traffic) ----
    #pragma unroll
    for (int i = 0; i < 6; ++i) {
        int idx = t + 512 * i;                       // 3072 chunks
        int m = idx / 48, c = idx - m * 48;
        const half8* src = (c < 24) ? ((const half8*)(xf + (size_t)gi[m] * 192) + c)
                                    : ((const half8*)(qe + (size_t)qi[m] * 192) + (c - 24));
        *(half8*)(hA + m * PADK + c * 8) = *src;
    }
    __syncthreads();

    const _Float16* abase = hA + ln * PADK + lq * 8;

    // ---- layers 0,1: 384 -> 384, gelu, in-place. wave w owns 48-col slice ----
    #pragma unroll 1
    for (int L = 0; L < 2; ++L) {
        const _Float16* __restrict__ Wp = L ? Wp1 : Wp0;
        const float* __restrict__ bias = L ? b1 : b0;

        const _Float16* wb[3];
        #pragma unroll
        for (int nt = 0; nt < 3; ++nt)
            wb[nt] = Wp + (size_t)((w * 3 + nt) * 12) * 512 + lane * 8;

        f32x4 acc[4][3];
        #pragma unroll
        for (int nt = 0; nt < 3; ++nt) {
            float bv = bias[w * 48 + nt * 16 + ln];
            #pragma unroll
            for (int mt = 0; mt < 4; ++mt)
                acc[mt][nt] = (f32x4){bv, bv, bv, bv};
        }
        #pragma unroll 2
        for (int ks = 0; ks < 12; ++ks) {
            half8 a[4], bf[3];
            #pragma unroll
            for (int mt = 0; mt < 4; ++mt)
                a[mt] = *(const half8*)(abase + mt * 16 * PADK + ks * 32);
            #pragma unroll
            for (int nt = 0; nt < 3; ++nt)
                bf[nt] = *(const half8*)(wb[nt] + ks * 512);
            #pragma unroll
            for (int nt = 0; nt < 3; ++nt)
                #pragma unroll
                for (int mt = 0; mt < 4; ++mt)
                    acc[mt][nt] = __builtin_amdgcn_mfma_f32_16x16x32_f16(a[mt], bf[nt], acc[mt][nt], 0, 0, 0);
        }
        __syncthreads();   // all waves done reading hA
        _Float16* wbase = hA + (lq * 4) * PADK + w * 48 + ln;
        #pragma unroll
        for (int mt = 0; mt < 4; ++mt)
            #pragma unroll
            for (int nt = 0; nt < 3; ++nt)
                #pragma unroll
                for (int r = 0; r < 4; ++r)
                    wbase[(mt * 16 + r) * PADK + nt * 16] = (_Float16)gelu_f(acc[mt][nt][r]);
        __syncthreads();
    }

    // ---- layer 2: 384 -> 192. wave w: n-slice (w&3)*48, m-half (w>>2)*32 ----
    {
        const int n0 = (w & 3) * 48;
        const int mh = (w >> 2) * 2;                 // m-tile base (units of 16 rows)
        const _Float16* wb[3];
        #pragma unroll
        for (int nt = 0; nt < 3; ++nt)
            wb[nt] = Wp2 + (size_t)(((w & 3) * 3 + nt) * 12) * 512 + lane * 8;

        f32x4 acc[2][3];
        #pragma unroll
        for (int nt = 0; nt < 3; ++nt) {
            float bv = b2[n0 + nt * 16 + ln];
            #pragma unroll
            for (int mt = 0; mt < 2; ++mt)
                acc[mt][nt] = (f32x4){bv, bv, bv, bv};
        }
        const _Float16* abase2 = hA + (mh * 16 + ln) * PADK + lq * 8;
        #pragma unroll 2
        for (int ks = 0; ks < 12; ++ks) {
            half8 a[2], bf[3];
            #pragma unroll
            for (int mt = 0; mt < 2; ++mt)
                a[mt] = *(const half8*)(abase2 + mt * 16 * PADK + ks * 32);
            #pragma unroll
            for (int nt = 0; nt < 3; ++nt)
                bf[nt] = *(const half8*)(wb[nt] + ks * 512);
            #pragma unroll
            for (int nt = 0; nt < 3; ++nt)
                #pragma unroll
                for (int mt = 0; mt < 2; ++mt)
                    acc[mt][nt] = __builtin_amdgcn_mfma_f32_16x16x32_f16(a[mt], bf[nt], acc[mt][nt], 0, 0, 0);
        }
        __syncthreads();   // all waves done reading hA; safe to overwrite as h2
        float* sbase = h2 + (mh * 16 + lq * 4) * 192 + n0 + ln;
        #pragma unroll
        for (int mt = 0; mt < 2; ++mt)
            #pragma unroll
            for (int nt = 0; nt < 3; ++nt)
                #pragma unroll
                for (int r = 0; r < 4; ++r)
                    sbase[(mt * 16 + r) * 192 + nt * 16] = acc[mt][nt][r];
        __syncthreads();
    }

    // ---- segment reduce within block (qidx sorted), 2 row-halves, then atomics ----
    if (t < 384) {
        int half = t >= 192;
        int col = t - half * 192;
        int mlo = half * 32, mhi = mlo + 32;
        float a = 0.0f;
        for (int m = mlo; m < mhi; ++m) {
            a += h2[m * 192 + col];
            if (m == mhi - 1 || qi[m + 1] != qi[m]) {
                atomicAdd(&seg[(size_t)qi[m] * 192 + col], a);
                a = 0.0f;
            }
        }
    } else if (t < 386) {
        int half = t - 384;
        int mlo = half * 32, mhi = mlo + 32;
        float run = 1.0f;
        for (int m = mlo + 1; m < mhi; ++m) {
            if (qi[m] != qi[m - 1]) { atomicAdd(&cnt[qi[m - 1]], run); run = 1.0f; }
            else run += 1.0f;
        }
        atomicAdd(&cnt[qi[mhi - 1]], run);
    }
}

// ---------------- head: m = seg/max(cnt,1); out = gelu(m@W0+b0)@W1+b1 ----------------
#define PSK 196   // ps row stride (f32)

__global__ __launch_bounds__(256, 2) void head_kernel(
    const float* __restrict__ seg, const float* __restrict__ cnt,
    const _Float16* __restrict__ Wp0, const float* __restrict__ b0,
    const float* __restrict__ w1, const float* __restrict__ b1,
    float* __restrict__ out)
{
    __shared__ _Float16 hA[64 * PK];     // 25600 B
    __shared__ float ps[64 * PSK];       // 50176 B
    __shared__ float w1s[192 * 4];
    __shared__ float invc[64];
    const int t = threadIdx.x;
    const int r0 = blockIdx.x * 64;
    const int lane = t & 63;
    const int w = t >> 6;
    const int ln = lane & 15, lq = lane >> 4;

    if (t < 64) invc[t] = 1.0f / fmaxf(cnt[r0 + t], 1.0f);
    if (t < 192) ((float4*)w1s)[t] = ((const float4*)w1)[t];
    __syncthreads();

    #pragma unroll
    for (int i = 0; i < 12; ++i) {
        int idx = t + 256 * i;
        int r = idx / 48, c4 = idx - r * 48;
        float inv = invc[r];
        float4 v = ((const float4*)(seg + (size_t)(r0 + r) * 192))[c4];
        half4v hv; hv[0] = (_Float16)(v.x * inv); hv[1] = (_Float16)(v.y * inv);
        hv[2] = (_Float16)(v.z * inv); hv[3] = (_Float16)(v.w * inv);
        *(half4v*)(hA + r * PK + c4 * 4) = hv;
    }
    __syncthreads();

    f32x4 acc[4][3];
    #pragma unroll
    for (int nt = 0; nt < 3; ++nt) {
        float bv = b0[w * 48 + nt * 16 + ln];
        #pragma unroll
        for (int mt = 0; mt < 4; ++mt) acc[mt][nt] = (f32x4){bv, bv, bv, bv};
    }
    const _Float16* abase = hA + ln * PK + lq * 8;
    #pragma unroll 2
    for (int ks = 0; ks < 6; ++ks) {
        half8 a[4], bf[3];
        #pragma unroll
        for (int mt = 0; mt < 4; ++mt)
            a[mt] = *(const half8*)(abase + mt * 16 * PK + ks * 32);
        #pragma unroll
        for (int nt = 0; nt < 3; ++nt)
            bf[nt] = *(const half8*)(Wp0 + (size_t)(((w * 3 + nt) * 6 + ks) * 512 + lane * 8));
        #pragma unroll
        for (int nt = 0; nt < 3; ++nt)
            #pragma unroll
            for (int mt = 0; mt < 4; ++mt)
                acc[mt][nt] = __builtin_amdgcn_mfma_f32_16x16x32_f16(a[mt], bf[nt], acc[mt][nt], 0, 0, 0);
    }
    #pragma unroll
    for (int mt = 0; mt < 4; ++mt)
        #pragma unroll
        for (int nt = 0; nt < 3; ++nt)
            #pragma unroll
            for (int r = 0; r < 4; ++r) {
                int m = mt * 16 + lq * 4 + r;
                int n = w * 48 + nt * 16 + ln;
                ps[m * PSK + n] = gelu_f(acc[mt][nt][r]);
            }
    __syncthreads();

    // layer1: 192 -> 4, one thread per (row, out-col), float4 LDS reads
    {
        int r = t >> 2, oo = t & 3;
        float a = b1[oo];
        const float4* prow = (const float4*)(ps + r * PSK);
        #pragma unroll 4
        for (int k4 = 0; k4 < 48; ++k4) {
            float4 v = prow[k4];
            a = fmaf(v.x, w1s[(k4 * 4 + 0) * 4 + oo], a);
            a = fmaf(v.y, w1s[(k4 * 4 + 1) * 4 + oo], a);
            a = fmaf(v.z, w1s[(k4 * 4 + 2) * 4 + oo], a);
            a = fmaf(v.w, w1s[(k4 * 4 + 3) * 4 + oo], a);
        }
        out[(size_t)(r0 + r) * 4 + oo] = a;
    }
}

extern "C" void kernel_launch(void* const* d_in, const int* in_sizes, int n_in,
                              void* d_out, int out_size, void* d_ws, size_t ws_size,
                              hipStream_t stream) {
    (void)in_sizes; (void)n_in; (void)out_size; (void)ws_size;
    const float* x       = (const float*)d_in[0];
    const float* qpos    = (const float*)d_in[1];
    const int*   edges   = (const int*)d_in[2];
    const float* proj_w  = (const float*)d_in[3];
    const float* proj_b  = (const float*)d_in[4];
    const float* msg0_w  = (const float*)d_in[5];
    const float* msg0_b  = (const float*)d_in[6];
    const float* msg1_w  = (const float*)d_in[7];
    const float* msg1_b  = (const float*)d_in[8];
    const float* msg2_w  = (const float*)d_in[9];
    const float* msg2_b  = (const float*)d_in[10];
    const float* pred0_w = (const float*)d_in[11];
    const float* pred0_b = (const float*)d_in[12];
    const float* pred1_w = (const float*)d_in[13];
    const float* pred1_b = (const float*)d_in[14];
    float* out = (float*)d_out;

    // ws layout (bytes):
    //  xf  f16: 12582912                    @ 0
    //  qe  f16: 12582912                    @ 12582912
    //  seg f32: 25165824                    @ 25165824   (cnt follows contiguously)
    //  cnt f32: 131072                      @ 50331648
    //  Wp0 f16: 294912                      @ 50462720
    //  Wp1 f16: 294912                      @ 50757632
    //  Wp2 f16: 147456                      @ 51052544
    //  WpP f16: 73728                       @ 51200000
    //  WpH f16: 73728                       @ 51273728
    char* ws = (char*)d_ws;
    _Float16* xf  = (_Float16*)(ws);
    _Float16* qe  = (_Float16*)(ws + 12582912);
    float*    seg = (float*)(ws + 25165824);
    float*    cnt = (float*)(ws + 50331648);
    _Float16* Wp0 = (_Float16*)(ws + 50462720);
    _Float16* Wp1 = (_Float16*)(ws + 50757632);
    _Float16* Wp2 = (_Float16*)(ws + 51052544);
    _Float16* WpP = (_Float16*)(ws + 51200000);
    _Float16* WpH = (_Float16*)(ws + 51273728);

    hipMemsetAsync(seg, 0, 25165824 + 131072, stream);
    prep_kernel<<<12504, 256, 0, stream>>>(qpos, qe, proj_w, WpP,
                                           msg0_w, Wp0, msg1_w, Wp1,
                                           msg2_w, Wp2, pred0_w, WpH);
    proj_mfma_kernel<<<512, 256, 0, stream>>>(x, WpP, proj_b, xf);
    edge_mlp_kernel<<<4096, 512, 0, stream>>>(xf, qe, edges,
                                              Wp0, msg0_b, Wp1, msg1_b, Wp2, msg2_b,
                                              seg, cnt);
    head_kernel<<<512, 256, 0, stream>>>(seg, cnt, WpH, pred0_b,
                                         pred1_w, pred1_b, out);
}

// Round 9
// 383.063 us; speedup vs baseline: 1.0734x; 1.0734x over previous
//
#include <hip/hip_runtime.h>
#include <math.h>

// Problem constants
#define N_Q    32768
#define N_E    262144
// dims: IN=EMB=192, concat=384, 2*HID=384, BOT=192, PREDH=192, OUT=4

typedef _Float16 half8 __attribute__((ext_vector_type(8)));
typedef _Float16 half4v __attribute__((ext_vector_type(4)));
typedef float f32x4 __attribute__((ext_vector_type(4)));

// A&S 7.1.25 erf (|eps|<=2.5e-5). gelu(x)=0.5(x+|x|*erf(|x|/sqrt2))
__device__ __forceinline__ float gelu_f(float x) {
    float ax = fabsf(x);
    float t = __builtin_amdgcn_rcpf(fmaf(0.33269070724668f, ax, 1.0f));
    float poly = t * fmaf(t, fmaf(t, 0.7478556f, -0.0958798f), 0.3480242f);
    float e = exp2f(-0.72134752044448f * ax * ax);
    float u = fmaf(-poly, e, 1.0f);          // erf(z)
    return 0.5f * fmaf(ax, u, x);
}

// ---------------- sincos embedding -> f16 (hw sin/cos on revolutions) ----------------
__global__ __launch_bounds__(256) void embed_kernel(const float* __restrict__ qpos,
                                                    _Float16* __restrict__ qe) {
    int gid = blockIdx.x * 256 + threadIdx.x;   // covers N_Q*96: (q, d, i)
    int q = gid / 96, r = gid - q * 96;
    int d = r >> 5, i = r & 31;
    float omega = exp2f(-(float)i * 0.41524101186092029f);  // log2(10000)/32
    float arg = qpos[q * 3 + d] * omega;
    float rev = arg * 0.15915494309189535f;                  // radians -> revolutions
    rev = rev - floorf(rev);
    float s = __builtin_amdgcn_sinf(rev);
    float c = __builtin_amdgcn_cosf(rev);
    int base = q * 192 + d * 64 + i;
    qe[base] = (_Float16)s;
    qe[base + 32] = (_Float16)c;
}

// ---- pack W[K][N] fp32 -> fragment-order f16 ----
// Per (n_tile, ks) a 1KB block; lane l holds B[k=ks*32+(l>>4)*8+j][n=n_tile*16+(l&15)]
__device__ __forceinline__ void pack_one(const float* __restrict__ W,
                                         _Float16* __restrict__ Wp,
                                         int K, int N, int blk0, int tid) {
    int u = blk0 * 256 + tid;                   // one half8 per thread
    if (u * 8 >= K * N) return;
    int l = u & 63, blk = u >> 6;
    int nks = K >> 5;
    int ntile = blk / nks, ks = blk - ntile * nks;
    int n = ntile * 16 + (l & 15);
    int k0 = ks * 32 + (l >> 4) * 8;
    half8 v;
    #pragma unroll
    for (int j = 0; j < 8; ++j) v[j] = (_Float16)W[(size_t)(k0 + j) * N + n];
    *(half8*)(Wp + (size_t)u * 8) = v;
}

__global__ __launch_bounds__(256) void pack_all_kernel(
    const float* __restrict__ pw,  _Float16* __restrict__ WpP,
    const float* __restrict__ m0,  _Float16* __restrict__ Wp0,
    const float* __restrict__ m1,  _Float16* __restrict__ Wp1,
    const float* __restrict__ m2,  _Float16* __restrict__ Wp2,
    const float* __restrict__ hw,  _Float16* __restrict__ WpH) {
    int b = blockIdx.x, t = threadIdx.x;
    if      (b < 18)  pack_one(pw, WpP, 192, 192, b,        t);
    else if (b < 90)  pack_one(m0, Wp0, 384, 384, b - 18,   t);
    else if (b < 162) pack_one(m1, Wp1, 384, 384, b - 90,   t);
    else if (b < 198) pack_one(m2, Wp2, 384, 192, b - 162,  t);
    else              pack_one(hw, WpH, 192, 192, b - 198,  t);
}

// ---------------- proj: xf = f16(x @ proj_w + proj_b), via MFMA ----------------
#define PK 200   // hA row stride (f16), 400 B

__global__ __launch_bounds__(256, 2) void proj_mfma_kernel(
    const float* __restrict__ x, const _Float16* __restrict__ Wp,
    const float* __restrict__ bias, _Float16* __restrict__ xf)
{
    __shared__ _Float16 hA[64 * PK];   // 25600 B
    const int t = threadIdx.x;
    const int r0 = blockIdx.x * 64;
    const int lane = t & 63;
    const int w = t >> 6;
    const int ln = lane & 15, lq = lane >> 4;

    #pragma unroll
    for (int i = 0; i < 12; ++i) {                 // 3072 float4s
        int idx = t + 256 * i;
        int r = idx / 48, c4 = idx - r * 48;
        float4 v = ((const float4*)(x + (size_t)(r0 + r) * 192))[c4];
        half4v hv; hv[0] = (_Float16)v.x; hv[1] = (_Float16)v.y;
        hv[2] = (_Float16)v.z; hv[3] = (_Float16)v.w;
        *(half4v*)(hA + r * PK + c4 * 4) = hv;
    }
    __syncthreads();

    f32x4 acc[4][3];
    #pragma unroll
    for (int nt = 0; nt < 3; ++nt) {
        float bv = bias[w * 48 + nt * 16 + ln];
        #pragma unroll
        for (int mt = 0; mt < 4; ++mt) acc[mt][nt] = (f32x4){bv, bv, bv, bv};
    }
    #pragma unroll 2
    for (int ks = 0; ks < 6; ++ks) {
        half8 a[4], bf[3];
        #pragma unroll
        for (int mt = 0; mt < 4; ++mt)
            a[mt] = *(const half8*)(hA + (mt * 16 + ln) * PK + ks * 32 + lq * 8);
        #pragma unroll
        for (int nt = 0; nt < 3; ++nt)
            bf[nt] = *(const half8*)(Wp + (size_t)(((w * 3 + nt) * 6 + ks) * 512 + lane * 8));
        #pragma unroll
        for (int nt = 0; nt < 3; ++nt)
            #pragma unroll
            for (int mt = 0; mt < 4; ++mt)
                acc[mt][nt] = __builtin_amdgcn_mfma_f32_16x16x32_f16(a[mt], bf[nt], acc[mt][nt], 0, 0, 0);
    }
    #pragma unroll
    for (int mt = 0; mt < 4; ++mt)
        #pragma unroll
        for (int nt = 0; nt < 3; ++nt)
            #pragma unroll
            for (int r = 0; r < 4; ++r) {
                int m = mt * 16 + lq * 4 + r;
                int n = w * 48 + nt * 16 + ln;
                xf[(size_t)(r0 + m) * 192 + n] = (_Float16)acc[mt][nt][r];
            }
}

// ---------------- fused edge MLP via f16 MFMA, 512 threads / 8 waves ----------------
#define PADK 392   // hA row stride in f16 elements (784 B)

__global__ __launch_bounds__(512, 6) void edge_mlp_kernel(
    const _Float16* __restrict__ xf, const _Float16* __restrict__ qe,
    const int* __restrict__ edges,
    const _Float16* __restrict__ Wp0, const float* __restrict__ b0,
    const _Float16* __restrict__ Wp1, const float* __restrict__ b1,
    const _Float16* __restrict__ Wp2, const float* __restrict__ b2,
    float* __restrict__ seg, float* __restrict__ cnt)
{
    __shared__ _Float16 hA[64 * PADK];   // 50176 B; aliased as f32 h2[64][192] later
    __shared__ int qi[64], gi[64];
    float* h2 = (float*)hA;

    const int t = threadIdx.x;
    const int e0 = blockIdx.x * 64;
    const int lane = t & 63;
    const int w = t >> 6;                // 0..7
    const int ln = lane & 15;            // MFMA n / m low index
    const int lq = lane >> 4;            // quad

    if (t < 64) {
        qi[t] = edges[2 * (e0 + t)];
        gi[t] = edges[2 * (e0 + t) + 1];
    }
    __syncthreads();

    // ---- gather concat(xf[g], qe[q]) into padded LDS, 16B chunks ----
    #pragma unroll
    for (int i = 0; i < 6; ++i) {
        int idx = t + 512 * i;                       // 3072 chunks
        int m = idx / 48, c = idx - m * 48;
        const half8* src = (c < 24) ? ((const half8*)(xf + (size_t)gi[m] * 192) + c)
                                    : ((const half8*)(qe + (size_t)qi[m] * 192) + (c - 24));
        *(half8*)(hA + m * PADK + c * 8) = *src;
    }
    __syncthreads();

    // ---- layers 0,1: 384 -> 384, gelu, in-place. wave w owns 48-col slice ----
    #pragma unroll 1
    for (int L = 0; L < 2; ++L) {
        const _Float16* __restrict__ Wp = L ? Wp1 : Wp0;
        const float* __restrict__ bias = L ? b1 : b0;

        f32x4 acc[4][3];
        #pragma unroll
        for (int nt = 0; nt < 3; ++nt) {
            float bv = bias[w * 48 + nt * 16 + ln];
            #pragma unroll
            for (int mt = 0; mt < 4; ++mt)
                acc[mt][nt] = (f32x4){bv, bv, bv, bv};
        }
        #pragma unroll 2
        for (int ks = 0; ks < 12; ++ks) {
            half8 a[4], bf[3];
            #pragma unroll
            for (int mt = 0; mt < 4; ++mt)
                a[mt] = *(const half8*)(hA + (mt * 16 + ln) * PADK + ks * 32 + lq * 8);
            #pragma unroll
            for (int nt = 0; nt < 3; ++nt)
                bf[nt] = *(const half8*)(Wp + (size_t)(((w * 3 + nt) * 12 + ks) * 512 + lane * 8));
            #pragma unroll
            for (int nt = 0; nt < 3; ++nt)
                #pragma unroll
                for (int mt = 0; mt < 4; ++mt)
                    acc[mt][nt] = __builtin_amdgcn_mfma_f32_16x16x32_f16(a[mt], bf[nt], acc[mt][nt], 0, 0, 0);
        }
        __syncthreads();   // all waves done reading hA
        #pragma unroll
        for (int mt = 0; mt < 4; ++mt)
            #pragma unroll
            for (int nt = 0; nt < 3; ++nt)
                #pragma unroll
                for (int r = 0; r < 4; ++r) {
                    int m = mt * 16 + lq * 4 + r;
                    int n = w * 48 + nt * 16 + ln;
                    hA[m * PADK + n] = (_Float16)gelu_f(acc[mt][nt][r]);
                }
        __syncthreads();
    }

    // ---- layer 2: 384 -> 192. wave w: n-slice (w&3)*48, m-half (w>>2)*32 ----
    {
        const int n0 = (w & 3) * 48;
        const int mh = (w >> 2) * 2;                 // m-tile base (units of 16 rows)
        f32x4 acc[2][3];
        #pragma unroll
        for (int nt = 0; nt < 3; ++nt) {
            float bv = b2[n0 + nt * 16 + ln];
            #pragma unroll
            for (int mt = 0; mt < 2; ++mt)
                acc[mt][nt] = (f32x4){bv, bv, bv, bv};
        }
        #pragma unroll 2
        for (int ks = 0; ks < 12; ++ks) {
            half8 a[2], bf[3];
            #pragma unroll
            for (int mt = 0; mt < 2; ++mt)
                a[mt] = *(const half8*)(hA + ((mh + mt) * 16 + ln) * PADK + ks * 32 + lq * 8);
            #pragma unroll
            for (int nt = 0; nt < 3; ++nt)
                bf[nt] = *(const half8*)(Wp2 + (size_t)((((w & 3) * 3 + nt) * 12 + ks) * 512 + lane * 8));
            #pragma unroll
            for (int nt = 0; nt < 3; ++nt)
                #pragma unroll
                for (int mt = 0; mt < 2; ++mt)
                    acc[mt][nt] = __builtin_amdgcn_mfma_f32_16x16x32_f16(a[mt], bf[nt], acc[mt][nt], 0, 0, 0);
        }
        __syncthreads();   // all waves done reading hA; safe to overwrite as h2
        #pragma unroll
        for (int mt = 0; mt < 2; ++mt)
            #pragma unroll
            for (int nt = 0; nt < 3; ++nt)
                #pragma unroll
                for (int r = 0; r < 4; ++r) {
                    int m = (mh + mt) * 16 + lq * 4 + r;
                    int n = n0 + nt * 16 + ln;
                    h2[m * 192 + n] = acc[mt][nt][r];
                }
        __syncthreads();
    }

    // ---- segment reduce within block (qidx sorted), 2 row-halves, then atomics ----
    if (t < 384) {
        int half = t >= 192;
        int col = t - half * 192;
        int mlo = half * 32, mhi = mlo + 32;
        float a = 0.0f;
        for (int m = mlo; m < mhi; ++m) {
            a += h2[m * 192 + col];
            if (m == mhi - 1 || qi[m + 1] != qi[m]) {
                atomicAdd(&seg[(size_t)qi[m] * 192 + col], a);
                a = 0.0f;
            }
        }
    } else if (t < 386) {
        int half = t - 384;
        int mlo = half * 32, mhi = mlo + 32;
        float run = 1.0f;
        for (int m = mlo + 1; m < mhi; ++m) {
            if (qi[m] != qi[m - 1]) { atomicAdd(&cnt[qi[m - 1]], run); run = 1.0f; }
            else run += 1.0f;
        }
        atomicAdd(&cnt[qi[mhi - 1]], run);
    }
}

// ---------------- head: m = seg/max(cnt,1); out = gelu(m@W0+b0)@W1+b1 ----------------
#define PSK 196   // ps row stride (f32)

__global__ __launch_bounds__(256, 2) void head_kernel(
    const float* __restrict__ seg, const float* __restrict__ cnt,
    const _Float16* __restrict__ Wp0, const float* __restrict__ b0,
    const float* __restrict__ w1, const float* __restrict__ b1,
    float* __restrict__ out)
{
    __shared__ _Float16 hA[64 * PK];     // 25600 B
    __shared__ float ps[64 * PSK];       // 50176 B
    __shared__ float w1s[192 * 4];
    __shared__ float invc[64];
    const int t = threadIdx.x;
    const int r0 = blockIdx.x * 64;
    const int lane = t & 63;
    const int w = t >> 6;
    const int ln = lane & 15, lq = lane >> 4;

    if (t < 64) invc[t] = 1.0f / fmaxf(cnt[r0 + t], 1.0f);
    if (t < 192) ((float4*)w1s)[t] = ((const float4*)w1)[t];
    __syncthreads();

    #pragma unroll
    for (int i = 0; i < 12; ++i) {
        int idx = t + 256 * i;
        int r = idx / 48, c4 = idx - r * 48;
        float inv = invc[r];
        float4 v = ((const float4*)(seg + (size_t)(r0 + r) * 192))[c4];
        half4v hv; hv[0] = (_Float16)(v.x * inv); hv[1] = (_Float16)(v.y * inv);
        hv[2] = (_Float16)(v.z * inv); hv[3] = (_Float16)(v.w * inv);
        *(half4v*)(hA + r * PK + c4 * 4) = hv;
    }
    __syncthreads();

    f32x4 acc[4][3];
    #pragma unroll
    for (int nt = 0; nt < 3; ++nt) {
        float bv = b0[w * 48 + nt * 16 + ln];
        #pragma unroll
        for (int mt = 0; mt < 4; ++mt) acc[mt][nt] = (f32x4){bv, bv, bv, bv};
    }
    #pragma unroll 2
    for (int ks = 0; ks < 6; ++ks) {
        half8 a[4], bf[3];
        #pragma unroll
        for (int mt = 0; mt < 4; ++mt)
            a[mt] = *(const half8*)(hA + (mt * 16 + ln) * PK + ks * 32 + lq * 8);
        #pragma unroll
        for (int nt = 0; nt < 3; ++nt)
            bf[nt] = *(const half8*)(Wp0 + (size_t)(((w * 3 + nt) * 6 + ks) * 512 + lane * 8));
        #pragma unroll
        for (int nt = 0; nt < 3; ++nt)
            #pragma unroll
            for (int mt = 0; mt < 4; ++mt)
                acc[mt][nt] = __builtin_amdgcn_mfma_f32_16x16x32_f16(a[mt], bf[nt], acc[mt][nt], 0, 0, 0);
    }
    #pragma unroll
    for (int mt = 0; mt < 4; ++mt)
        #pragma unroll
        for (int nt = 0; nt < 3; ++nt)
            #pragma unroll
            for (int r = 0; r < 4; ++r) {
                int m = mt * 16 + lq * 4 + r;
                int n = w * 48 + nt * 16 + ln;
                ps[m * PSK + n] = gelu_f(acc[mt][nt][r]);
            }
    __syncthreads();

    // layer1: 192 -> 4, one thread per (row, out-col), float4 LDS reads
    {
        int r = t >> 2, oo = t & 3;
        float a = b1[oo];
        const float4* prow = (const float4*)(ps + r * PSK);
        #pragma unroll 4
        for (int k4 = 0; k4 < 48; ++k4) {
            float4 v = prow[k4];
            a = fmaf(v.x, w1s[(k4 * 4 + 0) * 4 + oo], a);
            a = fmaf(v.y, w1s[(k4 * 4 + 1) * 4 + oo], a);
            a = fmaf(v.z, w1s[(k4 * 4 + 2) * 4 + oo], a);
            a = fmaf(v.w, w1s[(k4 * 4 + 3) * 4 + oo], a);
        }
        out[(size_t)(r0 + r) * 4 + oo] = a;
    }
}

extern "C" void kernel_launch(void* const* d_in, const int* in_sizes, int n_in,
                              void* d_out, int out_size, void* d_ws, size_t ws_size,
                              hipStream_t stream) {
    (void)in_sizes; (void)n_in; (void)out_size; (void)ws_size;
    const float* x       = (const float*)d_in[0];
    const float* qpos    = (const float*)d_in[1];
    const int*   edges   = (const int*)d_in[2];
    const float* proj_w  = (const float*)d_in[3];
    const float* proj_b  = (const float*)d_in[4];
    const float* msg0_w  = (const float*)d_in[5];
    const float* msg0_b  = (const float*)d_in[6];
    const float* msg1_w  = (const float*)d_in[7];
    const float* msg1_b  = (const float*)d_in[8];
    const float* msg2_w  = (const float*)d_in[9];
    const float* msg2_b  = (const float*)d_in[10];
    const float* pred0_w = (const float*)d_in[11];
    const float* pred0_b = (const float*)d_in[12];
    const float* pred1_w = (const float*)d_in[13];
    const float* pred1_b = (const float*)d_in[14];
    float* out = (float*)d_out;

    // ws layout (bytes):
    //  xf  f16: 12582912                    @ 0
    //  qe  f16: 12582912                    @ 12582912
    //  seg f32: 25165824                    @ 25165824   (cnt follows contiguously)
    //  cnt f32: 131072                      @ 50331648
    //  Wp0 f16: 294912                      @ 50462720
    //  Wp1 f16: 294912                      @ 50757632
    //  Wp2 f16: 147456                      @ 51052544
    //  WpP f16: 73728                       @ 51200000
    //  WpH f16: 73728                       @ 51273728
    char* ws = (char*)d_ws;
    _Float16* xf  = (_Float16*)(ws);
    _Float16* qe  = (_Float16*)(ws + 12582912);
    float*    seg = (float*)(ws + 25165824);
    float*    cnt = (float*)(ws + 50331648);
    _Float16* Wp0 = (_Float16*)(ws + 50462720);
    _Float16* Wp1 = (_Float16*)(ws + 50757632);
    _Float16* Wp2 = (_Float16*)(ws + 51052544);
    _Float16* WpP = (_Float16*)(ws + 51200000);
    _Float16* WpH = (_Float16*)(ws + 51273728);

    // R5-anchored launch structure (best measured): memset first, embed and
    // pack as SEPARATE kernels (R6's prep fusion correlated with +33MB edge
    // FETCH and +75MB WRITE; never recovered by partial reverts).
    hipMemsetAsync(seg, 0, 25165824 + 131072, stream);   // seg + cnt
    embed_kernel<<<12288, 256, 0, stream>>>(qpos, qe);   // 32768*96/256
    pack_all_kernel<<<216, 256, 0, stream>>>(proj_w, WpP, msg0_w, Wp0,
                                             msg1_w, Wp1, msg2_w, Wp2,
                                             pred0_w, WpH);
    proj_mfma_kernel<<<512, 256, 0, stream>>>(x, WpP, proj_b, xf);
    edge_mlp_kernel<<<4096, 512, 0, stream>>>(xf, qe, edges,
                                              Wp0, msg0_b, Wp1, msg1_b, Wp2, msg2_b,
                                              seg, cnt);
    head_kernel<<<512, 256, 0, stream>>>(seg, cnt, WpH, pred0_b,
                                         pred1_w, pred1_b, out);
}

// Round 10
// 380.940 us; speedup vs baseline: 1.0794x; 1.0056x over previous
//
#include <hip/hip_runtime.h>
#include <math.h>

// Problem constants
#define N_Q    32768
#define N_E    262144
// dims: IN=EMB=192, concat=384, 2*HID=384, BOT=192, PREDH=192, OUT=4

typedef _Float16 half8 __attribute__((ext_vector_type(8)));
typedef _Float16 half4v __attribute__((ext_vector_type(4)));
typedef float f32x4 __attribute__((ext_vector_type(4)));

// A&S 7.1.25 erf (|eps|<=2.5e-5). gelu(x)=0.5(x+|x|*erf(|x|/sqrt2))
__device__ __forceinline__ float gelu_f(float x) {
    float ax = fabsf(x);
    float t = __builtin_amdgcn_rcpf(fmaf(0.33269070724668f, ax, 1.0f));
    float poly = t * fmaf(t, fmaf(t, 0.7478556f, -0.0958798f), 0.3480242f);
    float e = exp2f(-0.72134752044448f * ax * ax);
    float u = fmaf(-poly, e, 1.0f);          // erf(z)
    return 0.5f * fmaf(ax, u, x);
}

// ---------------- sincos embedding -> f16 (hw sin/cos on revolutions) ----------------
__global__ __launch_bounds__(256) void embed_kernel(const float* __restrict__ qpos,
                                                    _Float16* __restrict__ qe) {
    int gid = blockIdx.x * 256 + threadIdx.x;   // covers N_Q*96: (q, d, i)
    int q = gid / 96, r = gid - q * 96;
    int d = r >> 5, i = r & 31;
    float omega = exp2f(-(float)i * 0.41524101186092029f);  // log2(10000)/32
    float arg = qpos[q * 3 + d] * omega;
    float rev = arg * 0.15915494309189535f;                  // radians -> revolutions
    rev = rev - floorf(rev);
    float s = __builtin_amdgcn_sinf(rev);
    float c = __builtin_amdgcn_cosf(rev);
    int base = q * 192 + d * 64 + i;
    qe[base] = (_Float16)s;
    qe[base + 32] = (_Float16)c;
}

// ---- pack W[K][N] fp32 -> fragment-order f16 ----
// Per (n_tile, ks) a 1KB block; lane l holds B[k=ks*32+(l>>4)*8+j][n=n_tile*16+(l&15)]
__device__ __forceinline__ void pack_one(const float* __restrict__ W,
                                         _Float16* __restrict__ Wp,
                                         int K, int N, int blk0, int tid) {
    int u = blk0 * 256 + tid;                   // one half8 per thread
    if (u * 8 >= K * N) return;
    int l = u & 63, blk = u >> 6;
    int nks = K >> 5;
    int ntile = blk / nks, ks = blk - ntile * nks;
    int n = ntile * 16 + (l & 15);
    int k0 = ks * 32 + (l >> 4) * 8;
    half8 v;
    #pragma unroll
    for (int j = 0; j < 8; ++j) v[j] = (_Float16)W[(size_t)(k0 + j) * N + n];
    *(half8*)(Wp + (size_t)u * 8) = v;
}

__global__ __launch_bounds__(256) void pack_all_kernel(
    const float* __restrict__ pw,  _Float16* __restrict__ WpP,
    const float* __restrict__ m0,  _Float16* __restrict__ Wp0,
    const float* __restrict__ m1,  _Float16* __restrict__ Wp1,
    const float* __restrict__ m2,  _Float16* __restrict__ Wp2,
    const float* __restrict__ hw,  _Float16* __restrict__ WpH) {
    int b = blockIdx.x, t = threadIdx.x;
    if      (b < 18)  pack_one(pw, WpP, 192, 192, b,        t);
    else if (b < 90)  pack_one(m0, Wp0, 384, 384, b - 18,   t);
    else if (b < 162) pack_one(m1, Wp1, 384, 384, b - 90,   t);
    else if (b < 198) pack_one(m2, Wp2, 384, 192, b - 162,  t);
    else              pack_one(hw, WpH, 192, 192, b - 198,  t);
}

// ---------------- proj: xf = f16(x @ proj_w + proj_b), via MFMA ----------------
#define PK 200   // hA row stride (f16), 400 B

__global__ __launch_bounds__(256, 2) void proj_mfma_kernel(
    const float* __restrict__ x, const _Float16* __restrict__ Wp,
    const float* __restrict__ bias, _Float16* __restrict__ xf)
{
    __shared__ _Float16 hA[64 * PK];   // 25600 B
    const int t = threadIdx.x;
    const int r0 = blockIdx.x * 64;
    const int lane = t & 63;
    const int w = t >> 6;
    const int ln = lane & 15, lq = lane >> 4;

    #pragma unroll
    for (int i = 0; i < 12; ++i) {                 // 3072 float4s
        int idx = t + 256 * i;
        int r = idx / 48, c4 = idx - r * 48;
        float4 v = ((const float4*)(x + (size_t)(r0 + r) * 192))[c4];
        half4v hv; hv[0] = (_Float16)v.x; hv[1] = (_Float16)v.y;
        hv[2] = (_Float16)v.z; hv[3] = (_Float16)v.w;
        *(half4v*)(hA + r * PK + c4 * 4) = hv;
    }
    __syncthreads();

    f32x4 acc[4][3];
    #pragma unroll
    for (int nt = 0; nt < 3; ++nt) {
        float bv = bias[w * 48 + nt * 16 + ln];
        #pragma unroll
        for (int mt = 0; mt < 4; ++mt) acc[mt][nt] = (f32x4){bv, bv, bv, bv};
    }
    #pragma unroll 2
    for (int ks = 0; ks < 6; ++ks) {
        half8 a[4], bf[3];
        #pragma unroll
        for (int mt = 0; mt < 4; ++mt)
            a[mt] = *(const half8*)(hA + (mt * 16 + ln) * PK + ks * 32 + lq * 8);
        #pragma unroll
        for (int nt = 0; nt < 3; ++nt)
            bf[nt] = *(const half8*)(Wp + (size_t)(((w * 3 + nt) * 6 + ks) * 512 + lane * 8));
        #pragma unroll
        for (int nt = 0; nt < 3; ++nt)
            #pragma unroll
            for (int mt = 0; mt < 4; ++mt)
                acc[mt][nt] = __builtin_amdgcn_mfma_f32_16x16x32_f16(a[mt], bf[nt], acc[mt][nt], 0, 0, 0);
    }
    #pragma unroll
    for (int mt = 0; mt < 4; ++mt)
        #pragma unroll
        for (int nt = 0; nt < 3; ++nt)
            #pragma unroll
            for (int r = 0; r < 4; ++r) {
                int m = mt * 16 + lq * 4 + r;
                int n = w * 48 + nt * 16 + ln;
                xf[(size_t)(r0 + m) * 192 + n] = (_Float16)acc[mt][nt][r];
            }
}

// ---------------- fused edge MLP via f16 MFMA, 512 threads / 8 waves ----------------
// OPERAND-SWAPPED MFMA (R10): A/B fragment lane maps are identical for
// mfma_f32_16x16x32_f16, so mfma(bf, a, acc) computes (h·W)^T: lane's C col
// = edge index, its 4 regs = 4 CONSECUTIVE output features -> vector epilogue.
#define PADK 392   // hA row stride in f16 elements (784 B)
#define H2S  196   // h2 row stride in f32 (== PADK/2 dwords; 196%32=4 -> <=2-way)

__global__ __launch_bounds__(512, 6) void edge_mlp_kernel(
    const _Float16* __restrict__ xf, const _Float16* __restrict__ qe,
    const int* __restrict__ edges,
    const _Float16* __restrict__ Wp0, const float* __restrict__ b0,
    const _Float16* __restrict__ Wp1, const float* __restrict__ b1,
    const _Float16* __restrict__ Wp2, const float* __restrict__ b2,
    float* __restrict__ seg, float* __restrict__ cnt)
{
    __shared__ _Float16 hA[64 * PADK];   // 50176 B; aliased as f32 h2[64][H2S] later
    __shared__ int qi[64], gi[64];
    float* h2 = (float*)hA;

    const int t = threadIdx.x;
    const int e0 = blockIdx.x * 64;
    const int lane = t & 63;
    const int w = t >> 6;                // 0..7
    const int ln = lane & 15;            // C col (= edge index after swap)
    const int lq = lane >> 4;            // quad: C rows lq*4..lq*4+3 (= features)

    if (t < 64) {
        qi[t] = edges[2 * (e0 + t)];
        gi[t] = edges[2 * (e0 + t) + 1];
    }
    __syncthreads();

    // ---- gather concat(xf[g], qe[q]) into padded LDS, 16B chunks ----
    #pragma unroll
    for (int i = 0; i < 6; ++i) {
        int idx = t + 512 * i;                       // 3072 chunks
        int m = idx / 48, c = idx - m * 48;
        const half8* src = (c < 24) ? ((const half8*)(xf + (size_t)gi[m] * 192) + c)
                                    : ((const half8*)(qe + (size_t)qi[m] * 192) + (c - 24));
        *(half8*)(hA + m * PADK + c * 8) = *src;
    }
    __syncthreads();

    // ---- layers 0,1: 384 -> 384, gelu, in-place. wave w owns 48-col slice ----
    #pragma unroll 1
    for (int L = 0; L < 2; ++L) {
        const _Float16* __restrict__ Wp = L ? Wp1 : Wp0;
        const float* __restrict__ bias = L ? b1 : b0;
        const int n0 = w * 48;

        f32x4 acc[4][3];
        #pragma unroll
        for (int nt = 0; nt < 3; ++nt) {
            f32x4 bv4 = *(const f32x4*)(bias + n0 + nt * 16 + lq * 4);
            #pragma unroll
            for (int mt = 0; mt < 4; ++mt)
                acc[mt][nt] = bv4;
        }
        #pragma unroll 2
        for (int ks = 0; ks < 12; ++ks) {
            half8 a[4], bf[3];
            #pragma unroll
            for (int mt = 0; mt < 4; ++mt)
                a[mt] = *(const half8*)(hA + (mt * 16 + ln) * PADK + ks * 32 + lq * 8);
            #pragma unroll
            for (int nt = 0; nt < 3; ++nt)
                bf[nt] = *(const half8*)(Wp + (size_t)(((w * 3 + nt) * 12 + ks) * 512 + lane * 8));
            #pragma unroll
            for (int nt = 0; nt < 3; ++nt)
                #pragma unroll
                for (int mt = 0; mt < 4; ++mt)
                    acc[mt][nt] = __builtin_amdgcn_mfma_f32_16x16x32_f16(bf[nt], a[mt], acc[mt][nt], 0, 0, 0);
        }
        __syncthreads();   // all waves done reading hA
        // lane writes edge row (mt*16+ln), features n0+nt*16+lq*4..+3 (b64)
        _Float16* wbase = hA + ln * PADK + n0 + lq * 4;
        #pragma unroll
        for (int mt = 0; mt < 4; ++mt)
            #pragma unroll
            for (int nt = 0; nt < 3; ++nt) {
                half4v hv;
                #pragma unroll
                for (int r = 0; r < 4; ++r) hv[r] = (_Float16)gelu_f(acc[mt][nt][r]);
                *(half4v*)(wbase + mt * 16 * PADK + nt * 16) = hv;
            }
        __syncthreads();
    }

    // ---- layer 2: 384 -> 192. wave w: n-slice (w&3)*48, m-half (w>>2)*32 ----
    {
        const int n0 = (w & 3) * 48;
        const int mh = (w >> 2) * 2;                 // m-tile base (units of 16 rows)
        f32x4 acc[2][3];
        #pragma unroll
        for (int nt = 0; nt < 3; ++nt) {
            f32x4 bv4 = *(const f32x4*)(b2 + n0 + nt * 16 + lq * 4);
            #pragma unroll
            for (int mt = 0; mt < 2; ++mt)
                acc[mt][nt] = bv4;
        }
        #pragma unroll 2
        for (int ks = 0; ks < 12; ++ks) {
            half8 a[2], bf[3];
            #pragma unroll
            for (int mt = 0; mt < 2; ++mt)
                a[mt] = *(const half8*)(hA + ((mh + mt) * 16 + ln) * PADK + ks * 32 + lq * 8);
            #pragma unroll
            for (int nt = 0; nt < 3; ++nt)
                bf[nt] = *(const half8*)(Wp2 + (size_t)((((w & 3) * 3 + nt) * 12 + ks) * 512 + lane * 8));
            #pragma unroll
            for (int nt = 0; nt < 3; ++nt)
                #pragma unroll
                for (int mt = 0; mt < 2; ++mt)
                    acc[mt][nt] = __builtin_amdgcn_mfma_f32_16x16x32_f16(bf[nt], a[mt], acc[mt][nt], 0, 0, 0);
        }
        __syncthreads();   // all waves done reading hA; safe to overwrite as h2
        // lane writes edge row ((mh+mt)*16+ln), features n0+nt*16+lq*4..+3 (b128)
        float* sbase = h2 + ((size_t)(mh * 16 + ln)) * H2S + n0 + lq * 4;
        #pragma unroll
        for (int mt = 0; mt < 2; ++mt)
            #pragma unroll
            for (int nt = 0; nt < 3; ++nt)
                *(f32x4*)(sbase + mt * 16 * H2S + nt * 16) = acc[mt][nt];
        __syncthreads();
    }

    // ---- segment reduce within block (qidx sorted), 2 row-halves, then atomics ----
    if (t < 384) {
        int half = t >= 192;
        int col = t - half * 192;
        int mlo = half * 32, mhi = mlo + 32;
        float a = 0.0f;
        for (int m = mlo; m < mhi; ++m) {
            a += h2[m * H2S + col];
            if (m == mhi - 1 || qi[m + 1] != qi[m]) {
                atomicAdd(&seg[(size_t)qi[m] * 192 + col], a);
                a = 0.0f;
            }
        }
    } else if (t < 386) {
        int half = t - 384;
        int mlo = half * 32, mhi = mlo + 32;
        float run = 1.0f;
        for (int m = mlo + 1; m < mhi; ++m) {
            if (qi[m] != qi[m - 1]) { atomicAdd(&cnt[qi[m - 1]], run); run = 1.0f; }
            else run += 1.0f;
        }
        atomicAdd(&cnt[qi[mhi - 1]], run);
    }
}

// ---------------- head: m = seg/max(cnt,1); out = gelu(m@W0+b0)@W1+b1 ----------------
#define PSK 196   // ps row stride (f32)

__global__ __launch_bounds__(256, 2) void head_kernel(
    const float* __restrict__ seg, const float* __restrict__ cnt,
    const _Float16* __restrict__ Wp0, const float* __restrict__ b0,
    const float* __restrict__ w1, const float* __restrict__ b1,
    float* __restrict__ out)
{
    __shared__ _Float16 hA[64 * PK];     // 25600 B
    __shared__ float ps[64 * PSK];       // 50176 B
    __shared__ float w1s[192 * 4];
    __shared__ float invc[64];
    const int t = threadIdx.x;
    const int r0 = blockIdx.x * 64;
    const int lane = t & 63;
    const int w = t >> 6;
    const int ln = lane & 15, lq = lane >> 4;

    if (t < 64) invc[t] = 1.0f / fmaxf(cnt[r0 + t], 1.0f);
    if (t < 192) ((float4*)w1s)[t] = ((const float4*)w1)[t];
    __syncthreads();

    #pragma unroll
    for (int i = 0; i < 12; ++i) {
        int idx = t + 256 * i;
        int r = idx / 48, c4 = idx - r * 48;
        float inv = invc[r];
        float4 v = ((const float4*)(seg + (size_t)(r0 + r) * 192))[c4];
        half4v hv; hv[0] = (_Float16)(v.x * inv); hv[1] = (_Float16)(v.y * inv);
        hv[2] = (_Float16)(v.z * inv); hv[3] = (_Float16)(v.w * inv);
        *(half4v*)(hA + r * PK + c4 * 4) = hv;
    }
    __syncthreads();

    f32x4 acc[4][3];
    #pragma unroll
    for (int nt = 0; nt < 3; ++nt) {
        float bv = b0[w * 48 + nt * 16 + ln];
        #pragma unroll
        for (int mt = 0; mt < 4; ++mt) acc[mt][nt] = (f32x4){bv, bv, bv, bv};
    }
    #pragma unroll 2
    for (int ks = 0; ks < 6; ++ks) {
        half8 a[4], bf[3];
        #pragma unroll
        for (int mt = 0; mt < 4; ++mt)
            a[mt] = *(const half8*)(hA + (mt * 16 + ln) * PK + ks * 32 + lq * 8);
        #pragma unroll
        for (int nt = 0; nt < 3; ++nt)
            bf[nt] = *(const half8*)(Wp0 + (size_t)(((w * 3 + nt) * 6 + ks) * 512 + lane * 8));
        #pragma unroll
        for (int nt = 0; nt < 3; ++nt)
            #pragma unroll
            for (int mt = 0; mt < 4; ++mt)
                acc[mt][nt] = __builtin_amdgcn_mfma_f32_16x16x32_f16(a[mt], bf[nt], acc[mt][nt], 0, 0, 0);
    }
    #pragma unroll
    for (int mt = 0; mt < 4; ++mt)
        #pragma unroll
        for (int nt = 0; nt < 3; ++nt)
            #pragma unroll
            for (int r = 0; r < 4; ++r) {
                int m = mt * 16 + lq * 4 + r;
                int n = w * 48 + nt * 16 + ln;
                ps[m * PSK + n] = gelu_f(acc[mt][nt][r]);
            }
    __syncthreads();

    // layer1: 192 -> 4, one thread per (row, out-col), float4 LDS reads
    {
        int r = t >> 2, oo = t & 3;
        float a = b1[oo];
        const float4* prow = (const float4*)(ps + r * PSK);
        #pragma unroll 4
        for (int k4 = 0; k4 < 48; ++k4) {
            float4 v = prow[k4];
            a = fmaf(v.x, w1s[(k4 * 4 + 0) * 4 + oo], a);
            a = fmaf(v.y, w1s[(k4 * 4 + 1) * 4 + oo], a);
            a = fmaf(v.z, w1s[(k4 * 4 + 2) * 4 + oo], a);
            a = fmaf(v.w, w1s[(k4 * 4 + 3) * 4 + oo], a);
        }
        out[(size_t)(r0 + r) * 4 + oo] = a;
    }
}

extern "C" void kernel_launch(void* const* d_in, const int* in_sizes, int n_in,
                              void* d_out, int out_size, void* d_ws, size_t ws_size,
                              hipStream_t stream) {
    (void)in_sizes; (void)n_in; (void)out_size; (void)ws_size;
    const float* x       = (const float*)d_in[0];
    const float* qpos    = (const float*)d_in[1];
    const int*   edges   = (const int*)d_in[2];
    const float* proj_w  = (const float*)d_in[3];
    const float* proj_b  = (const float*)d_in[4];
    const float* msg0_w  = (const float*)d_in[5];
    const float* msg0_b  = (const float*)d_in[6];
    const float* msg1_w  = (const float*)d_in[7];
    const float* msg1_b  = (const float*)d_in[8];
    const float* msg2_w  = (const float*)d_in[9];
    const float* msg2_b  = (const float*)d_in[10];
    const float* pred0_w = (const float*)d_in[11];
    const float* pred0_b = (const float*)d_in[12];
    const float* pred1_w = (const float*)d_in[13];
    const float* pred1_b = (const float*)d_in[14];
    float* out = (float*)d_out;

    // ws layout (bytes):
    //  xf  f16: 12582912                    @ 0
    //  qe  f16: 12582912                    @ 12582912
    //  seg f32: 25165824                    @ 25165824   (cnt follows contiguously)
    //  cnt f32: 131072                      @ 50331648
    //  Wp0 f16: 294912                      @ 50462720
    //  Wp1 f16: 294912                      @ 50757632
    //  Wp2 f16: 147456                      @ 51052544
    //  WpP f16: 73728                       @ 51200000
    //  WpH f16: 73728                       @ 51273728
    char* ws = (char*)d_ws;
    _Float16* xf  = (_Float16*)(ws);
    _Float16* qe  = (_Float16*)(ws + 12582912);
    float*    seg = (float*)(ws + 25165824);
    float*    cnt = (float*)(ws + 50331648);
    _Float16* Wp0 = (_Float16*)(ws + 50462720);
    _Float16* Wp1 = (_Float16*)(ws + 50757632);
    _Float16* Wp2 = (_Float16*)(ws + 51052544);
    _Float16* WpP = (_Float16*)(ws + 51200000);
    _Float16* WpH = (_Float16*)(ws + 51273728);

    // R5-anchored launch structure (best measured; R9 re-verified): memset
    // first, embed and pack as SEPARATE kernels (R6's prep fusion cost
    // +33MB edge FETCH / +75MB WRITE).
    hipMemsetAsync(seg, 0, 25165824 + 131072, stream);   // seg + cnt
    embed_kernel<<<12288, 256, 0, stream>>>(qpos, qe);   // 32768*96/256
    pack_all_kernel<<<216, 256, 0, stream>>>(proj_w, WpP, msg0_w, Wp0,
                                             msg1_w, Wp1, msg2_w, Wp2,
                                             pred0_w, WpH);
    proj_mfma_kernel<<<512, 256, 0, stream>>>(x, WpP, proj_b, xf);
    edge_mlp_kernel<<<4096, 512, 0, stream>>>(xf, qe, edges,
                                              Wp0, msg0_b, Wp1, msg1_b, Wp2, msg2_b,
                                              seg, cnt);
    head_kernel<<<512, 256, 0, stream>>>(seg, cnt, WpH, pred0_b,
                                         pred1_w, pred1_b, out);
}